// Round 1
// baseline (3408.904 us; speedup 1.0000x reference)
//
#include <hip/hip_runtime.h>
#include <math.h>

// Problem constants
#define B_N 2048
#define T_N 128
#define C_N 3
#define J_N 25
#define E_N 64
#define TC  (T_N*C_N)    // 384 rows per batch after flattening (t,c)
#define TCJ (TC*J_N)     // 9600 floats per batch

// Workspace layout (float offsets). Total ~17.3 MB.
#define H_OFF      0          // h [2048*25]
#define HN_OFF     51200      // normalized h [2048*25]
#define LOHI_OFF   102400     // lo/hi as uint bits [2]
#define DEATHS_OFF 102404     // MST edge weights [2047]
#define D_OFF      131072     // distance matrix [2048*2048]

__global__ void k_init(float* ws) {
    if (threadIdx.x == 0) {
        unsigned int* lohi = (unsigned int*)(ws + LOHI_OFF);
        lohi[0] = 0x7F800000u;  // +inf  (h >= 0, uint bits order == float order)
        lohi[1] = 0u;           // 0.0f
    }
}

// One block per batch b: reduce x[b] over (t,c) -> M[25], then h[b,j], then
// block-local min/max -> global atomics.
__global__ void k_reduce(const float* __restrict__ x, float* __restrict__ ws) {
    __shared__ float part[8][32];
    __shared__ float Mj[32];
    __shared__ float hv_sh[32];
    const int j = threadIdx.x;   // 0..31 (j < 25 active)
    const int yg = threadIdx.y;  // 0..7
    const int b = blockIdx.x;
    const float* xb = x + (size_t)b * TCJ;

    float s = 0.f;
    if (j < J_N) {
        for (int r = yg; r < TC; r += 8) s += xb[r * J_N + j];
    }
    part[yg][j] = s;
    __syncthreads();
    if (yg == 0) {
        float t = 0.f;
        #pragma unroll
        for (int k = 0; k < 8; ++k) t += part[k][j];
        Mj[j] = t * (1.0f / TC);
    }
    __syncthreads();
    if (yg == 0 && j < J_N) {
        float mj = Mj[j];
        float acc = 0.f;
        #pragma unroll
        for (int i = 0; i < J_N; ++i) { float d = Mj[i] - mj; acc += d * d; }
        float hv = sqrtf(acc);
        ws[H_OFF + b * J_N + j] = hv;
        hv_sh[j] = hv;
    }
    __syncthreads();
    if (yg == 0 && j == 0) {
        float lo = hv_sh[0], hi = hv_sh[0];
        #pragma unroll
        for (int i = 1; i < J_N; ++i) { lo = fminf(lo, hv_sh[i]); hi = fmaxf(hi, hv_sh[i]); }
        unsigned int* lohi = (unsigned int*)(ws + LOHI_OFF);
        atomicMin(&lohi[0], __float_as_uint(lo));
        atomicMax(&lohi[1], __float_as_uint(hi));
    }
}

__global__ void k_norm(float* ws) {
    int i = blockIdx.x * 256 + threadIdx.x;
    if (i >= B_N * J_N) return;
    const unsigned int* lohi = (const unsigned int*)(ws + LOHI_OFF);
    float lo = __uint_as_float(lohi[0]);
    float hi = __uint_as_float(lohi[1]);
    float rng = hi - lo;
    float v = ws[H_OFF + i];
    v = (rng > 1e-8f) ? (v - lo) / rng : 0.f;
    ws[HN_OFF + i] = v;
}

// 16x16 tile of the 2048x2048 distance matrix per block.
__global__ void k_dist(float* ws) {
    __shared__ float A[16][26], Bsh[16][26];
    const int tx = threadIdx.x, ty = threadIdx.y;
    const int flat = ty * 16 + tx;
    const int rowA = blockIdx.x * 16, rowB = blockIdx.y * 16;
    const float* hn = ws + HN_OFF;
    for (int idx = flat; idx < 16 * J_N; idx += 256) {
        int r = idx / J_N, c = idx % J_N;
        A[r][c]   = hn[(rowA + r) * J_N + c];
        Bsh[r][c] = hn[(rowB + r) * J_N + c];
    }
    __syncthreads();
    float acc = 0.f;
    #pragma unroll
    for (int k = 0; k < J_N; ++k) {
        float d = A[ty][k] - Bsh[tx][k];
        acc += d * d;
    }
    float* D = ws + D_OFF;
    D[(size_t)(rowA + ty) * B_N + rowB + tx] = sqrtf(fmaxf(acc, 1e-12f));
}

// Single-block Prim's MST. Each thread owns 2 of the 2048 'mind' entries in
// registers; per iteration: block argmin (shuffle + LDS), fetch row j, update.
__global__ void __launch_bounds__(1024) k_prim(float* ws) {
    const float* D = ws + D_OFF;
    float* deaths = ws + DEATHS_OFF;
    const int tid = threadIdx.x;
    const int lane = tid & 63, wv = tid >> 6;
    __shared__ float swv[16];
    __shared__ int   swi[16];
    __shared__ int   sJ;

    float m0 = D[tid];
    float m1 = D[tid + 1024];
    bool t0 = (tid == 0), t1 = false;
    if (t0) m0 = INFINITY;

    for (int it = 0; it < B_N - 1; ++it) {
        // local argmin over owned pair (tie -> lower index, matching jnp.argmin)
        float bv; int bi_;
        if (m0 <= m1) { bv = m0; bi_ = tid; } else { bv = m1; bi_ = tid + 1024; }
        #pragma unroll
        for (int off = 32; off > 0; off >>= 1) {
            float ov = __shfl_down(bv, off);
            int   oi = __shfl_down(bi_, off);
            if (ov < bv || (ov == bv && oi < bi_)) { bv = ov; bi_ = oi; }
        }
        if (lane == 0) { swv[wv] = bv; swi[wv] = bi_; }
        __syncthreads();
        if (wv == 0) {
            float v = (lane < 16) ? swv[lane] : INFINITY;
            int  ix = (lane < 16) ? swi[lane] : 0;
            #pragma unroll
            for (int off = 8; off > 0; off >>= 1) {
                float ov = __shfl_down(v, off);
                int   oi = __shfl_down(ix, off);
                if (ov < v || (ov == v && oi < ix)) { v = ov; ix = oi; }
            }
            if (lane == 0) { sJ = ix; deaths[it] = v; }
        }
        __syncthreads();
        const int j = sJ;
        const float* row = D + (size_t)j * B_N;
        float r0 = row[tid], r1 = row[tid + 1024];
        if (!t0) m0 = fminf(m0, r0);
        if (!t1) m1 = fminf(m1, r1);
        if (tid == j)        { t0 = true; m0 = INFINITY; }
        if (tid + 1024 == j) { t1 = true; m1 = INFINITY; }
        __syncthreads();  // WAR: protect swv/swi/sJ before next iteration's writes
    }
}

// out[e] = exp(-s0^2*c0^2) * sum_p exp(-s1^2*(d_p - c1)^2)
__global__ void k_struct(const float* __restrict__ ws, const float* __restrict__ centres,
                         const float* __restrict__ sharp, float* __restrict__ out) {
    const int e = blockIdx.x, tid = threadIdx.x;
    const float* deaths = ws + DEATHS_OFF;
    const float c0 = centres[e * 2], c1 = centres[e * 2 + 1];
    const float s0 = sharp[e * 2],   s1 = sharp[e * 2 + 1];
    const float s1sq = s1 * s1;
    float acc = 0.f;
    for (int p = tid; p < B_N - 1; p += 256) {
        float d = deaths[p] - c1;
        acc += expf(-s1sq * d * d);
    }
    #pragma unroll
    for (int off = 32; off > 0; off >>= 1) acc += __shfl_down(acc, off);
    __shared__ float wsum[4];
    const int lane = tid & 63, w = tid >> 6;
    if (lane == 0) wsum[w] = acc;
    __syncthreads();
    if (tid == 0) {
        float tot = wsum[0] + wsum[1] + wsum[2] + wsum[3];
        out[e] = expf(-s0 * s0 * c0 * c0) * tot;
    }
}

extern "C" void kernel_launch(void* const* d_in, const int* in_sizes, int n_in,
                              void* d_out, int out_size, void* d_ws, size_t ws_size,
                              hipStream_t stream) {
    const float* x       = (const float*)d_in[0];
    const float* centres = (const float*)d_in[1];
    const float* sharp   = (const float*)d_in[2];
    float* out = (float*)d_out;
    float* ws  = (float*)d_ws;

    hipLaunchKernelGGL(k_init,   dim3(1),        dim3(64),       0, stream, ws);
    hipLaunchKernelGGL(k_reduce, dim3(B_N),      dim3(32, 8),    0, stream, x, ws);
    hipLaunchKernelGGL(k_norm,   dim3(200),      dim3(256),      0, stream, ws);
    hipLaunchKernelGGL(k_dist,   dim3(128, 128), dim3(16, 16),   0, stream, ws);
    hipLaunchKernelGGL(k_prim,   dim3(1),        dim3(1024),     0, stream, ws);
    hipLaunchKernelGGL(k_struct, dim3(E_N),      dim3(256),      0, stream, ws, centres, sharp, out);
}

// Round 2
// 340.055 us; speedup vs baseline: 10.0246x; 10.0246x over previous
//
#include <hip/hip_runtime.h>
#include <math.h>

// Problem constants
#define B_N 2048
#define T_N 128
#define C_N 3
#define J_N 25
#define E_N 64
#define TC  (T_N*C_N)    // 384 rows per batch after flattening (t,c)
#define TCJ (TC*J_N)     // 9600 floats per batch

// Workspace layout (float offsets). Total ~17.24 MB (fits prior 17.3 MB ws).
#define D_OFF      0                    // D [2048*2048] f32
#define H_OFF      4194304              // h [2048*25]
#define HN_OFF     (H_OFF + 51200)      // normalized h
#define LOHI_OFF   (HN_OFF + 51200)     // lo/hi uint bits [2]
#define COMP_OFF   (LOHI_OFF + 4)       // u32 comp[2048]
#define CNT_OFF    (COMP_OFF + 2048)    // u32 edge counter [1]
#define DEATHS_OFF (CNT_OFF + 4)        // f32 deaths[2047]
#define BEST_OFF   (DEATHS_OFF + 2048)  // u64 best[2048]  (even float offset -> 8B aligned)
#define CBEST_OFF  (BEST_OFF + 4096)    // u64 cbest[2048]

typedef unsigned long long u64;
#define U64MAX 0xFFFFFFFFFFFFFFFFull

__global__ void k_init(float* ws) {
    int i = blockIdx.x * 256 + threadIdx.x;
    unsigned* comp = (unsigned*)(ws + COMP_OFF);
    if (i < B_N) comp[i] = i;
    if (i == 0) {
        unsigned* lohi = (unsigned*)(ws + LOHI_OFF);
        lohi[0] = 0x7F800000u;  // +inf (h>=0: uint order == float order)
        lohi[1] = 0u;
        *(unsigned*)(ws + CNT_OFF) = 0u;
    }
}

// One block per batch b: reduce x[b] over (t,c) -> M[25], then h[b,j], min/max atomics.
__global__ void k_reduce(const float* __restrict__ x, float* __restrict__ ws) {
    __shared__ float part[8][32];
    __shared__ float Mj[32];
    __shared__ float hv_sh[32];
    const int j = threadIdx.x;   // 0..31 (j < 25 active)
    const int yg = threadIdx.y;  // 0..7
    const int b = blockIdx.x;
    const float* xb = x + (size_t)b * TCJ;

    float s = 0.f;
    if (j < J_N) {
        for (int r = yg; r < TC; r += 8) s += xb[r * J_N + j];
    }
    part[yg][j] = s;
    __syncthreads();
    if (yg == 0) {
        float t = 0.f;
        #pragma unroll
        for (int k = 0; k < 8; ++k) t += part[k][j];
        Mj[j] = t * (1.0f / TC);
    }
    __syncthreads();
    if (yg == 0 && j < J_N) {
        float mj = Mj[j];
        float acc = 0.f;
        #pragma unroll
        for (int i = 0; i < J_N; ++i) { float d = Mj[i] - mj; acc += d * d; }
        float hv = sqrtf(acc);
        ws[H_OFF + b * J_N + j] = hv;
        hv_sh[j] = hv;
    }
    __syncthreads();
    if (yg == 0 && j == 0) {
        float lo = hv_sh[0], hi = hv_sh[0];
        #pragma unroll
        for (int i = 1; i < J_N; ++i) { lo = fminf(lo, hv_sh[i]); hi = fmaxf(hi, hv_sh[i]); }
        unsigned* lohi = (unsigned*)(ws + LOHI_OFF);
        atomicMin(&lohi[0], __float_as_uint(lo));
        atomicMax(&lohi[1], __float_as_uint(hi));
    }
}

__global__ void k_norm(float* ws) {
    int i = blockIdx.x * 256 + threadIdx.x;
    if (i >= B_N * J_N) return;
    const unsigned* lohi = (const unsigned*)(ws + LOHI_OFF);
    float lo = __uint_as_float(lohi[0]);
    float hi = __uint_as_float(lohi[1]);
    float rng = hi - lo;
    float v = ws[H_OFF + i];
    v = (rng > 1e-8f) ? (v - lo) / rng : 0.f;
    ws[HN_OFF + i] = v;
}

// 16x16 tile of the 2048x2048 distance matrix per block.
__global__ void k_dist(float* ws) {
    __shared__ float A[16][26], Bsh[16][26];
    const int tx = threadIdx.x, ty = threadIdx.y;
    const int flat = ty * 16 + tx;
    const int rowA = blockIdx.x * 16, rowB = blockIdx.y * 16;
    const float* hn = ws + HN_OFF;
    for (int idx = flat; idx < 16 * J_N; idx += 256) {
        int r = idx / J_N, c = idx % J_N;
        A[r][c]   = hn[(rowA + r) * J_N + c];
        Bsh[r][c] = hn[(rowB + r) * J_N + c];
    }
    __syncthreads();
    float acc = 0.f;
    #pragma unroll
    for (int k = 0; k < J_N; ++k) {
        float d = A[ty][k] - Bsh[tx][k];
        acc += d * d;
    }
    float* D = ws + D_OFF;
    D[(size_t)(rowA + ty) * B_N + rowB + tx] = sqrtf(fmaxf(acc, 1e-12f));
}

// Boruvka step 1: per node i, min outgoing edge (to a different component).
// Key packs (weight_bits, min(i,j), max(i,j)) so both endpoints agree on the key.
__global__ void k_scan(float* __restrict__ ws) {
    const int i = blockIdx.x;
    const int lane = threadIdx.x;  // 0..63
    const float* D = ws + D_OFF;
    const unsigned* comp = (const unsigned*)(ws + COMP_OFF);
    const unsigned ci = comp[i];
    const float4* row4 = (const float4*)(D + (size_t)i * B_N);
    const uint4* comp4 = (const uint4*)comp;
    u64 best = U64MAX;
    #pragma unroll
    for (int k = 0; k < 8; ++k) {
        int q = k * 64 + lane;          // float4 index
        float4 w4 = row4[q];
        uint4 c4 = comp4[q];
        int j0 = q * 4;
        float wv[4] = {w4.x, w4.y, w4.z, w4.w};
        unsigned cv[4] = {c4.x, c4.y, c4.z, c4.w};
        #pragma unroll
        for (int m = 0; m < 4; ++m) {
            if (cv[m] != ci) {
                unsigned j = (unsigned)(j0 + m);
                unsigned a = min((unsigned)i, j), b = max((unsigned)i, j);
                u64 key = ((u64)__float_as_uint(wv[m]) << 32) | (a << 11) | b;
                if (key < best) best = key;
            }
        }
    }
    #pragma unroll
    for (int off = 32; off; off >>= 1) {
        u64 o = __shfl_down(best, off);
        if (o < best) best = o;
    }
    if (lane == 0) ((u64*)(ws + BEST_OFF))[i] = best;
}

// Boruvka step 2: per component c, min over its nodes' candidates.
__global__ void k_compmin(float* __restrict__ ws) {
    const int c = blockIdx.x;
    const int lane = threadIdx.x;  // 0..63
    const unsigned* comp = (const unsigned*)(ws + COMP_OFF);
    const u64* best = (const u64*)(ws + BEST_OFF);
    u64 m = U64MAX;
    #pragma unroll
    for (int k = 0; k < 32; ++k) {
        int i = k * 64 + lane;
        u64 v = best[i];
        if (comp[i] == (unsigned)c && v < m) m = v;
    }
    #pragma unroll
    for (int off = 32; off; off >>= 1) {
        u64 o = __shfl_down(m, off);
        if (o < m) m = o;
    }
    if (lane == 0) ((u64*)(ws + CBEST_OFF))[c] = m;
}

// Boruvka step 3 (single block): append edges (deduped), hook, break 2-cycles,
// pointer-jump in LDS, relabel comp.
__global__ void __launch_bounds__(1024) k_union(float* __restrict__ ws) {
    __shared__ unsigned par[B_N];
    __shared__ unsigned cnt_s;
    const u64* cbest = (const u64*)(ws + CBEST_OFF);
    unsigned* comp = (unsigned*)(ws + COMP_OFF);
    unsigned* gcnt = (unsigned*)(ws + CNT_OFF);
    float* deaths = ws + DEATHS_OFF;
    const int t = threadIdx.x;
    const unsigned base = *gcnt;
    if (t == 0) cnt_s = 0;
    __syncthreads();

    #pragma unroll
    for (int c = t; c < B_N; c += 1024) {
        u64 k = cbest[c];
        unsigned p = (unsigned)c;
        if (k != U64MAX) {
            unsigned a = (unsigned)((k >> 11) & 0x7FF);
            unsigned b = (unsigned)(k & 0x7FF);
            unsigned ca = comp[a], cb = comp[b];
            unsigned c2 = (ca == (unsigned)c) ? cb : ca;
            p = c2;
            bool add = true;
            if (cbest[c2] == k && c2 < (unsigned)c) add = false;  // mutual pick: smaller root adds
            if (add) {
                unsigned li = atomicAdd(&cnt_s, 1u);
                deaths[base + li] = __uint_as_float((unsigned)(k >> 32));
            }
        }
        par[c] = p;
    }
    __syncthreads();
    // break 2-cycles: smaller root self-roots
    #pragma unroll
    for (int c = t; c < B_N; c += 1024) {
        unsigned p = par[c];
        if (p != (unsigned)c && par[p] == (unsigned)c && (unsigned)c < p) par[c] = (unsigned)c;
    }
    __syncthreads();
    // pointer jumping (depth <= 2048 -> 11 iters)
    for (int it = 0; it < 11; ++it) {
        unsigned np0 = par[par[t]];
        unsigned np1 = par[par[t + 1024]];
        __syncthreads();
        par[t] = np0;
        par[t + 1024] = np1;
        __syncthreads();
    }
    // relabel nodes
    #pragma unroll
    for (int i = t; i < B_N; i += 1024) comp[i] = par[comp[i]];
    if (t == 0) *gcnt = base + cnt_s;
}

// out[e] = exp(-s0^2*c0^2) * sum_p exp(-s1^2*(d_p - c1)^2)
__global__ void k_struct(const float* __restrict__ ws, const float* __restrict__ centres,
                         const float* __restrict__ sharp, float* __restrict__ out) {
    const int e = blockIdx.x, tid = threadIdx.x;
    const float* deaths = ws + DEATHS_OFF;
    const float c0 = centres[e * 2], c1 = centres[e * 2 + 1];
    const float s0 = sharp[e * 2],   s1 = sharp[e * 2 + 1];
    const float s1sq = s1 * s1;
    float acc = 0.f;
    for (int p = tid; p < B_N - 1; p += 256) {
        float d = deaths[p] - c1;
        acc += expf(-s1sq * d * d);
    }
    #pragma unroll
    for (int off = 32; off > 0; off >>= 1) acc += __shfl_down(acc, off);
    __shared__ float wsum[4];
    const int lane = tid & 63, w = tid >> 6;
    if (lane == 0) wsum[w] = acc;
    __syncthreads();
    if (tid == 0) {
        float tot = wsum[0] + wsum[1] + wsum[2] + wsum[3];
        out[e] = expf(-s0 * s0 * c0 * c0) * tot;
    }
}

extern "C" void kernel_launch(void* const* d_in, const int* in_sizes, int n_in,
                              void* d_out, int out_size, void* d_ws, size_t ws_size,
                              hipStream_t stream) {
    const float* x       = (const float*)d_in[0];
    const float* centres = (const float*)d_in[1];
    const float* sharp   = (const float*)d_in[2];
    float* out = (float*)d_out;
    float* ws  = (float*)d_ws;

    hipLaunchKernelGGL(k_init,   dim3(8),        dim3(256),    0, stream, ws);
    hipLaunchKernelGGL(k_reduce, dim3(B_N),      dim3(32, 8),  0, stream, x, ws);
    hipLaunchKernelGGL(k_norm,   dim3(200),      dim3(256),    0, stream, ws);
    hipLaunchKernelGGL(k_dist,   dim3(128, 128), dim3(16, 16), 0, stream, ws);
    for (int r = 0; r < 11; ++r) {
        hipLaunchKernelGGL(k_scan,    dim3(B_N), dim3(64),   0, stream, ws);
        hipLaunchKernelGGL(k_compmin, dim3(B_N), dim3(64),   0, stream, ws);
        hipLaunchKernelGGL(k_union,   dim3(1),   dim3(1024), 0, stream, ws);
    }
    hipLaunchKernelGGL(k_struct, dim3(E_N),      dim3(256),  0, stream, ws, centres, sharp, out);
}

// Round 3
// 270.469 us; speedup vs baseline: 12.6037x; 1.2573x over previous
//
#include <hip/hip_runtime.h>
#include <math.h>

// Problem constants
#define B_N 2048
#define T_N 128
#define C_N 3
#define J_N 25
#define E_N 64
#define TC  (T_N*C_N)    // 384 rows per batch after flattening (t,c)
#define TCJ (TC*J_N)     // 9600 floats per batch

// Workspace layout (float offsets). Total ~16.8 MB.
#define D_OFF      0                    // D [2048*2048] f32 (raw-h distances)
#define H_OFF      4194304              // h [2048*25] (raw, unnormalized)
#define LOHI_OFF   (H_OFF + 51200)      // lo/hi uint bits [2]
#define COMP_OFF   (LOHI_OFF + 4)       // u32 comp[2048]
#define CNT_OFF    (COMP_OFF + 2048)    // u32 edge counter [1]
#define DEATHS_OFF (CNT_OFF + 4)        // f32 deaths[2047] (raw scale)
#define CBEST_OFF  (DEATHS_OFF + 2048)  // u64 cbest[2048] (even float off -> 8B aligned)

typedef unsigned long long u64;
#define U64MAX 0xFFFFFFFFFFFFFFFFull

__global__ void k_init(float* ws) {
    int i = blockIdx.x * 256 + threadIdx.x;
    unsigned* comp = (unsigned*)(ws + COMP_OFF);
    u64* cbest = (u64*)(ws + CBEST_OFF);
    if (i < B_N) { comp[i] = i; cbest[i] = U64MAX; }
    if (i == 0) {
        unsigned* lohi = (unsigned*)(ws + LOHI_OFF);
        lohi[0] = 0x7F800000u;  // +inf (h>=0: uint order == float order)
        lohi[1] = 0u;
        *(unsigned*)(ws + CNT_OFF) = 0u;
    }
}

// One block per batch b. Stage 9600 floats via coalesced float4 -> LDS, then
// column-reduce over (t,c), then h[b,j] and global min/max atomics.
__global__ void __launch_bounds__(256) k_reduce(const float* __restrict__ x,
                                                float* __restrict__ ws) {
    __shared__ float xs[TCJ];        // 38.4 KB
    __shared__ float part[8][32];
    __shared__ float Mj[32];
    __shared__ float hv_sh[32];
    const int t = threadIdx.x;       // 0..255
    const int b = blockIdx.x;
    const float4* xb4 = (const float4*)(x + (size_t)b * TCJ);
    float4* xs4 = (float4*)xs;
    for (int q = t; q < TCJ / 4; q += 256) xs4[q] = xb4[q];
    __syncthreads();

    const int j = t & 31, g = t >> 5;
    float s = 0.f;
    if (j < J_N) {
        for (int r = g; r < TC; r += 8) s += xs[r * J_N + j];
    }
    part[g][j] = s;
    __syncthreads();
    if (g == 0) {
        float tt = 0.f;
        #pragma unroll
        for (int k = 0; k < 8; ++k) tt += part[k][j];
        Mj[j] = tt * (1.0f / TC);
    }
    __syncthreads();
    if (g == 0 && j < J_N) {
        float mj = Mj[j];
        float acc = 0.f;
        #pragma unroll
        for (int i = 0; i < J_N; ++i) { float d = Mj[i] - mj; acc += d * d; }
        float hv = sqrtf(acc);
        ws[H_OFF + b * J_N + j] = hv;
        hv_sh[j] = hv;
    }
    __syncthreads();
    if (t == 0) {
        float lo = hv_sh[0], hi = hv_sh[0];
        #pragma unroll
        for (int i = 1; i < J_N; ++i) { lo = fminf(lo, hv_sh[i]); hi = fmaxf(hi, hv_sh[i]); }
        unsigned* lohi = (unsigned*)(ws + LOHI_OFF);
        atomicMin(&lohi[0], __float_as_uint(lo));
        atomicMax(&lohi[1], __float_as_uint(hi));
    }
}

// 16x16 tile of the 2048x2048 raw-h distance matrix per block.
// (Normalization is affine & identical per coordinate -> D_norm = rinv * D_raw;
//  MST is scale-invariant, rinv applied in k_struct.)
__global__ void k_dist(float* ws) {
    __shared__ float A[16][26], Bsh[16][26];
    const int tx = threadIdx.x, ty = threadIdx.y;
    const int flat = ty * 16 + tx;
    const int rowA = blockIdx.x * 16, rowB = blockIdx.y * 16;
    const float* h = ws + H_OFF;
    for (int idx = flat; idx < 16 * J_N; idx += 256) {
        int r = idx / J_N, c = idx % J_N;
        A[r][c]   = h[(rowA + r) * J_N + c];
        Bsh[r][c] = h[(rowB + r) * J_N + c];
    }
    __syncthreads();
    float acc = 0.f;
    #pragma unroll
    for (int k = 0; k < J_N; ++k) {
        float d = A[ty][k] - Bsh[tx][k];
        acc += d * d;
    }
    float* D = ws + D_OFF;
    D[(size_t)(rowA + ty) * B_N + rowB + tx] = sqrtf(fmaxf(acc, 1e-12f));
}

// Boruvka scan: per node i (one wave per node), min outgoing edge; atomicMin
// directly into cbest[comp[i]]. Key = (w_bits<<32)|(min<<11)|max so both
// endpoints of an undirected edge produce the identical key.
__global__ void __launch_bounds__(64) k_scan(float* __restrict__ ws) {
    const int i = blockIdx.x;
    const int lane = threadIdx.x;  // 0..63
    const float* D = ws + D_OFF;
    const unsigned* comp = (const unsigned*)(ws + COMP_OFF);
    const unsigned ci = comp[i];
    const float4* row4 = (const float4*)(D + (size_t)i * B_N);
    const uint4* comp4 = (const uint4*)comp;
    u64 best = U64MAX;
    #pragma unroll
    for (int k = 0; k < 8; ++k) {
        int q = k * 64 + lane;          // float4 index
        float4 w4 = row4[q];
        uint4 c4 = comp4[q];
        int j0 = q * 4;
        float wv[4] = {w4.x, w4.y, w4.z, w4.w};
        unsigned cv[4] = {c4.x, c4.y, c4.z, c4.w};
        #pragma unroll
        for (int m = 0; m < 4; ++m) {
            if (cv[m] != ci) {
                unsigned j = (unsigned)(j0 + m);
                unsigned a = min((unsigned)i, j), b = max((unsigned)i, j);
                u64 key = ((u64)__float_as_uint(wv[m]) << 32) | (a << 11) | b;
                if (key < best) best = key;
            }
        }
    }
    #pragma unroll
    for (int off = 32; off; off >>= 1) {
        u64 o = __shfl_down(best, off);
        if (o < best) best = o;
    }
    if (lane == 0 && best != U64MAX) atomicMin((u64*)(ws + CBEST_OFF) + ci, best);
}

// Boruvka union (single block): append edges (deduped), hook, break 2-cycles,
// pointer-jump in LDS, relabel comp, reset cbest.
__global__ void __launch_bounds__(1024) k_union(float* __restrict__ ws) {
    __shared__ unsigned par[B_N];
    __shared__ unsigned cnt_s;
    u64* cbest = (u64*)(ws + CBEST_OFF);
    unsigned* comp = (unsigned*)(ws + COMP_OFF);
    unsigned* gcnt = (unsigned*)(ws + CNT_OFF);
    float* deaths = ws + DEATHS_OFF;
    const int t = threadIdx.x;
    const unsigned base = *gcnt;
    if (t == 0) cnt_s = 0;
    __syncthreads();

    // Phase 1: all cbest reads (hook + dedup + edge append)
    #pragma unroll
    for (int c = t; c < B_N; c += 1024) {
        u64 k = cbest[c];
        unsigned p = (unsigned)c;
        if (k != U64MAX) {
            unsigned a = (unsigned)((k >> 11) & 0x7FF);
            unsigned b = (unsigned)(k & 0x7FF);
            unsigned ca = comp[a], cb = comp[b];
            unsigned c2 = (ca == (unsigned)c) ? cb : ca;
            p = c2;
            bool add = true;
            if (cbest[c2] == k && c2 < (unsigned)c) add = false;  // mutual pick: smaller root adds
            if (add) {
                unsigned li = atomicAdd(&cnt_s, 1u);
                deaths[base + li] = __uint_as_float((unsigned)(k >> 32));
            }
        }
        par[c] = p;
    }
    __syncthreads();
    // Phase 2: reset cbest for next round; break 2-cycles (smaller root self-roots)
    #pragma unroll
    for (int c = t; c < B_N; c += 1024) {
        cbest[c] = U64MAX;
        unsigned p = par[c];
        if (p != (unsigned)c && par[p] == (unsigned)c && (unsigned)c < p) par[c] = (unsigned)c;
    }
    __syncthreads();
    // Pointer jumping (depth <= 2047 -> 11 iters)
    for (int it = 0; it < 11; ++it) {
        unsigned np0 = par[par[t]];
        unsigned np1 = par[par[t + 1024]];
        __syncthreads();
        par[t] = np0;
        par[t + 1024] = np1;
        __syncthreads();
    }
    // Relabel nodes
    #pragma unroll
    for (int i = t; i < B_N; i += 1024) comp[i] = par[comp[i]];
    if (t == 0) *gcnt = base + cnt_s;
}

// out[e] = exp(-s0^2*c0^2) * sum_p exp(-s1^2*(rinv*death_p - c1)^2)
__global__ void k_struct(const float* __restrict__ ws, const float* __restrict__ centres,
                         const float* __restrict__ sharp, float* __restrict__ out) {
    const int e = blockIdx.x, tid = threadIdx.x;
    const float* deaths = ws + DEATHS_OFF;
    const unsigned* lohi = (const unsigned*)(ws + LOHI_OFF);
    float lo = __uint_as_float(lohi[0]);
    float hi = __uint_as_float(lohi[1]);
    float rng = hi - lo;
    float rinv = (rng > 1e-8f) ? 1.0f / rng : 0.0f;
    const float c0 = centres[e * 2], c1 = centres[e * 2 + 1];
    const float s0 = sharp[e * 2],   s1 = sharp[e * 2 + 1];
    const float s1sq = s1 * s1;
    float acc = 0.f;
    for (int p = tid; p < B_N - 1; p += 256) {
        float d = deaths[p] * rinv - c1;
        acc += expf(-s1sq * d * d);
    }
    #pragma unroll
    for (int off = 32; off > 0; off >>= 1) acc += __shfl_down(acc, off);
    __shared__ float wsum[4];
    const int lane = tid & 63, w = tid >> 6;
    if (lane == 0) wsum[w] = acc;
    __syncthreads();
    if (tid == 0) {
        float tot = wsum[0] + wsum[1] + wsum[2] + wsum[3];
        out[e] = expf(-s0 * s0 * c0 * c0) * tot;
    }
}

extern "C" void kernel_launch(void* const* d_in, const int* in_sizes, int n_in,
                              void* d_out, int out_size, void* d_ws, size_t ws_size,
                              hipStream_t stream) {
    const float* x       = (const float*)d_in[0];
    const float* centres = (const float*)d_in[1];
    const float* sharp   = (const float*)d_in[2];
    float* out = (float*)d_out;
    float* ws  = (float*)d_ws;

    hipLaunchKernelGGL(k_init,   dim3(8),        dim3(256),    0, stream, ws);
    hipLaunchKernelGGL(k_reduce, dim3(B_N),      dim3(256),    0, stream, x, ws);
    hipLaunchKernelGGL(k_dist,   dim3(128, 128), dim3(16, 16), 0, stream, ws);
    for (int r = 0; r < 11; ++r) {
        hipLaunchKernelGGL(k_scan,  dim3(B_N), dim3(64),   0, stream, ws);
        hipLaunchKernelGGL(k_union, dim3(1),   dim3(1024), 0, stream, ws);
    }
    hipLaunchKernelGGL(k_struct, dim3(E_N), dim3(256), 0, stream, ws, centres, sharp, out);
}